// Round 2
// baseline (445.827 us; speedup 1.0000x reference)
//
#include <hip/hip_runtime.h>
#include <hip/hip_bf16.h>

// ---------------------------------------------------------------------------
// GCN graph classifier: 2x GCNConv(relu) -> mean pool -> MLP -> sigmoid
// Strategy: build CSR (by dst) on device each launch (histogram + scan +
// scatter, int atomics only), then per-node gather aggregation (no fp32
// atomics). fp32 everywhere for correctness baseline.
// ---------------------------------------------------------------------------

#define WAVE 64

// ---- init: zero degree histogram and pooled accumulator -------------------
__global__ __launch_bounds__(256) void k_init(int* __restrict__ deg,
                                              float* __restrict__ pooled,
                                              int n) {
    int i = blockIdx.x * 256 + threadIdx.x;
    if (i < n) deg[i] = 0;
    if (i < 128) pooled[i] = 0.0f;
}

// ---- histogram of dst ------------------------------------------------------
__global__ __launch_bounds__(256) void k_hist(const int* __restrict__ dst,
                                              int* __restrict__ deg, int e) {
    int i = blockIdx.x * 256 + threadIdx.x;
    if (i < e) atomicAdd(&deg[dst[i]], 1);
}

// ---- dinv[i] = rsqrt(deg+1)  (self loop included) --------------------------
__global__ __launch_bounds__(256) void k_dinv(const int* __restrict__ deg,
                                              float* __restrict__ dinv, int n) {
    int i = blockIdx.x * 256 + threadIdx.x;
    if (i < n) dinv[i] = rsqrtf((float)deg[i] + 1.0f);
}

// ---- scan stage 1: per-block exclusive scan + block sums -------------------
__global__ __launch_bounds__(256) void k_scan1(const int* __restrict__ deg,
                                               int* __restrict__ rowptr,
                                               int* __restrict__ bsum, int n) {
    __shared__ int sh[256];
    int tid = threadIdx.x;
    int i = blockIdx.x * 256 + tid;
    int v = (i < n) ? deg[i] : 0;
    sh[tid] = v;
    __syncthreads();
    for (int ofs = 1; ofs < 256; ofs <<= 1) {
        int t = (tid >= ofs) ? sh[tid - ofs] : 0;
        __syncthreads();
        sh[tid] += t;
        __syncthreads();
    }
    if (i < n) rowptr[i] = sh[tid] - v;          // exclusive
    if (tid == 255) bsum[blockIdx.x] = sh[tid];  // inclusive total
}

// ---- scan stage 2: scan block sums (single block, nblocks <= 256) ----------
__global__ __launch_bounds__(256) void k_scan2(const int* __restrict__ bsum,
                                               int* __restrict__ bofs, int nb) {
    __shared__ int sh[256];
    int tid = threadIdx.x;
    int v = (tid < nb) ? bsum[tid] : 0;
    sh[tid] = v;
    __syncthreads();
    for (int ofs = 1; ofs < 256; ofs <<= 1) {
        int t = (tid >= ofs) ? sh[tid - ofs] : 0;
        __syncthreads();
        sh[tid] += t;
        __syncthreads();
    }
    bofs[tid] = sh[tid] - v;  // exclusive
}

// ---- scan stage 3: add block offsets; init cursor; rowptr[N]=E -------------
__global__ __launch_bounds__(256) void k_scan3(int* __restrict__ rowptr,
                                               const int* __restrict__ bofs,
                                               int* __restrict__ cursor, int n,
                                               int etot) {
    int i = blockIdx.x * 256 + threadIdx.x;
    if (i < n) {
        int rp = rowptr[i] + bofs[blockIdx.x];
        rowptr[i] = rp;
        cursor[i] = rp;
    }
    if (i == 0) rowptr[n] = etot;
}

// ---- scatter edges into CSR by dst ----------------------------------------
__global__ __launch_bounds__(256) void k_scatter(const int* __restrict__ ei,
                                                 int* __restrict__ cursor,
                                                 int* __restrict__ csr, int e) {
    int i = blockIdx.x * 256 + threadIdx.x;
    if (i < e) {
        int s = ei[i];
        int d = ei[e + i];
        int pos = atomicAdd(&cursor[d], 1);
        csr[pos] = s;
    }
}

// ---- fp32 GEMM: C[nrows,128] = A[nrows,128] @ W[128,128] -------------------
// W staged transposed (k-blocked float4) in LDS; 32 rows/block; 4x4 reg tile.
__global__ __launch_bounds__(256) void k_gemm128(const float* __restrict__ A,
                                                 const float* __restrict__ W,
                                                 float* __restrict__ C,
                                                 int nrows) {
    __shared__ float4 wt[32 * 128];  // 64KB: wt[kb*128+col] = W[4kb..4kb+3][col]
    __shared__ float xs[32 * 128];   // 16KB
    const int tid = threadIdx.x;
    const int r0 = blockIdx.x * 32;

    {
        const int col = tid & 127;
        for (int kb = tid >> 7; kb < 32; kb += 2) {
            const int k4 = kb * 4;
            wt[kb * 128 + col] =
                make_float4(W[(k4 + 0) * 128 + col], W[(k4 + 1) * 128 + col],
                            W[(k4 + 2) * 128 + col], W[(k4 + 3) * 128 + col]);
        }
    }
    for (int i = tid; i < 32 * 128 / 4; i += 256) {
        const int idx = i * 4;
        const int r = idx >> 7;
        const int c = idx & 127;
        float4 v = make_float4(0.f, 0.f, 0.f, 0.f);
        if (r0 + r < nrows) v = *(const float4*)&A[(size_t)(r0 + r) * 128 + c];
        *(float4*)&xs[idx] = v;
    }
    __syncthreads();

    const int cb = tid & 31;           // base col
    const int rbase = (tid >> 5) * 4;  // base row in tile
    float acc[4][4];
#pragma unroll
    for (int a = 0; a < 4; ++a)
#pragma unroll
        for (int b = 0; b < 4; ++b) acc[a][b] = 0.f;

    for (int kb = 0; kb < 32; ++kb) {
        float4 xv[4];
#pragma unroll
        for (int jr = 0; jr < 4; ++jr)
            xv[jr] = *(const float4*)&xs[(rbase + jr) * 128 + kb * 4];
#pragma unroll
        for (int jc = 0; jc < 4; ++jc) {
            const float4 wv = wt[kb * 128 + cb + 32 * jc];
#pragma unroll
            for (int jr = 0; jr < 4; ++jr) {
                acc[jr][jc] += xv[jr].x * wv.x + xv[jr].y * wv.y +
                               xv[jr].z * wv.z + xv[jr].w * wv.w;
            }
        }
    }
#pragma unroll
    for (int jr = 0; jr < 4; ++jr) {
        const int r = r0 + rbase + jr;
        if (r < nrows) {
#pragma unroll
            for (int jc = 0; jc < 4; ++jc)
                C[(size_t)r * 128 + cb + 32 * jc] = acc[jr][jc];
        }
    }
}

// ---- aggregate: one wave per node; fused self-loop + bias + relu -----------
__global__ __launch_bounds__(256) void k_aggregate(
    const float* __restrict__ h, const float* __restrict__ dinv,
    const int* __restrict__ rowptr, const int* __restrict__ csr,
    const float* __restrict__ bias, float* __restrict__ outp, int n) {
    const int node = blockIdx.x * 4 + (threadIdx.x >> 6);
    if (node >= n) return;
    const int lane = threadIdx.x & 63;
    const float di = dinv[node];

    const float2 bp = *(const float2*)&bias[lane * 2];
    const float2 hs = *(const float2*)&h[(size_t)node * 128 + lane * 2];
    float accx = hs.x * di * di;
    float accy = hs.y * di * di;

    int j = rowptr[node];
    const int end = rowptr[node + 1];
    for (; j + 1 < end; j += 2) {
        const int s0 = csr[j];
        const int s1 = csr[j + 1];
        const float n0 = dinv[s0] * di;
        const float n1 = dinv[s1] * di;
        const float2 a0 = *(const float2*)&h[(size_t)s0 * 128 + lane * 2];
        const float2 a1 = *(const float2*)&h[(size_t)s1 * 128 + lane * 2];
        accx += a0.x * n0 + a1.x * n1;
        accy += a0.y * n0 + a1.y * n1;
    }
    if (j < end) {
        const int s0 = csr[j];
        const float n0 = dinv[s0] * di;
        const float2 a0 = *(const float2*)&h[(size_t)s0 * 128 + lane * 2];
        accx += a0.x * n0;
        accy += a0.y * n0;
    }
    float2 r;
    r.x = fmaxf(accx + bp.x, 0.f);
    r.y = fmaxf(accy + bp.y, 0.f);
    *(float2*)&outp[(size_t)node * 128 + lane * 2] = r;
}

// ---- mean pool: per-block partial column sums + atomic combine -------------
__global__ __launch_bounds__(256) void k_pool(const float* __restrict__ a,
                                              float* __restrict__ pooled,
                                              int total) {
    __shared__ float part[256];
    const int tid = threadIdx.x;
    float s = 0.f;
    for (size_t idx = (size_t)blockIdx.x * 256 + tid; idx < (size_t)total;
         idx += (size_t)gridDim.x * 256)
        s += a[idx];
    part[tid] = s;
    __syncthreads();
    if (tid < 128) atomicAdd(&pooled[tid], part[tid] + part[tid + 128]);
}

// ---- MLP head: single block, 128 threads -----------------------------------
__global__ __launch_bounds__(128) void k_mlp(
    const float* __restrict__ pooled, const float* __restrict__ w11,
    const float* __restrict__ b11, const float* __restrict__ w12,
    const float* __restrict__ b12, const float* __restrict__ w21,
    const float* __restrict__ b21, const float* __restrict__ w22,
    const float* __restrict__ b22, float* __restrict__ out, int n) {
    __shared__ float g[128], t1[128], t2[128], t3[128], red[128];
    const int tid = threadIdx.x;
    g[tid] = pooled[tid] * (1.0f / (float)n);
    __syncthreads();

    float s = b11[tid];
    for (int k = 0; k < 128; ++k) s += g[k] * w11[k * 128 + tid];
    t1[tid] = fmaxf(s, 0.f);
    __syncthreads();

    s = b12[tid];
    for (int k = 0; k < 128; ++k) s += t1[k] * w12[k * 128 + tid];
    t2[tid] = s;
    __syncthreads();

    s = b21[tid];
    for (int k = 0; k < 128; ++k) s += t2[k] * w21[k * 128 + tid];
    t3[tid] = fmaxf(s, 0.f);
    __syncthreads();

    red[tid] = t3[tid] * w22[tid];
    __syncthreads();
    if (tid == 0) {
        float z = b22[0];
        for (int k = 0; k < 128; ++k) z += red[k];
        out[0] = 1.0f / (1.0f + expf(-z));
    }
}

extern "C" void kernel_launch(void* const* d_in, const int* in_sizes, int n_in,
                              void* d_out, int out_size, void* d_ws,
                              size_t ws_size, hipStream_t stream) {
    const float* x = (const float*)d_in[0];
    const int* ei = (const int*)d_in[1];
    const float* c1w = (const float*)d_in[2];
    const float* c1b = (const float*)d_in[3];
    const float* c2w = (const float*)d_in[4];
    const float* c2b = (const float*)d_in[5];
    const float* f1w1 = (const float*)d_in[6];
    const float* f1b1 = (const float*)d_in[7];
    const float* f1w2 = (const float*)d_in[8];
    const float* f1b2 = (const float*)d_in[9];
    const float* f2w1 = (const float*)d_in[10];
    const float* f2b1 = (const float*)d_in[11];
    const float* f2w2 = (const float*)d_in[12];
    const float* f2b2 = (const float*)d_in[13];
    float* out = (float*)d_out;

    const int N = in_sizes[0] / 128;
    const int E = in_sizes[1] / 2;

    char* ws = (char*)d_ws;
    size_t off = 0;
    auto alloc = [&](size_t b) {
        size_t o = off;
        off += (b + 255) & ~(size_t)255;
        return o;
    };
    int* deg = (int*)(ws + alloc((size_t)N * 4));
    float* dinv = (float*)(ws + alloc((size_t)N * 4));
    int* rowptr = (int*)(ws + alloc((size_t)(N + 1) * 4));
    int* cursor = (int*)(ws + alloc((size_t)N * 4));
    int* bsum = (int*)(ws + alloc(1024));
    int* bofs = (int*)(ws + alloc(1024));
    int* csr = (int*)(ws + alloc((size_t)E * 4));
    float* pooled = (float*)(ws + alloc(512));
    float* hbuf = (float*)(ws + alloc((size_t)N * 128 * 4));
    float* abuf = (float*)(ws + alloc((size_t)N * 128 * 4));

    const int nbN = (N + 255) / 256;   // 196 for N=50000
    const int nbE = (E + 255) / 256;   // 3125

    k_init<<<nbN, 256, 0, stream>>>(deg, pooled, N);
    k_hist<<<nbE, 256, 0, stream>>>(ei + E, deg, E);
    k_dinv<<<nbN, 256, 0, stream>>>(deg, dinv, N);
    k_scan1<<<nbN, 256, 0, stream>>>(deg, rowptr, bsum, N);
    k_scan2<<<1, 256, 0, stream>>>(bsum, bofs, nbN);
    k_scan3<<<nbN, 256, 0, stream>>>(rowptr, bofs, cursor, N, E);
    k_scatter<<<nbE, 256, 0, stream>>>(ei, cursor, csr, E);

    k_gemm128<<<(N + 31) / 32, 256, 0, stream>>>(x, c1w, hbuf, N);
    k_aggregate<<<(N + 3) / 4, 256, 0, stream>>>(hbuf, dinv, rowptr, csr, c1b,
                                                 abuf, N);
    k_gemm128<<<(N + 31) / 32, 256, 0, stream>>>(abuf, c2w, hbuf, N);
    k_aggregate<<<(N + 3) / 4, 256, 0, stream>>>(hbuf, dinv, rowptr, csr, c2b,
                                                 abuf, N);

    k_pool<<<256, 256, 0, stream>>>(abuf, pooled, N * 128);
    k_mlp<<<1, 128, 0, stream>>>(pooled, f1w1, f1b1, f1w2, f1b2, f2w1, f2b1,
                                 f2w2, f2b2, out, N);
}

// Round 3
// 320.128 us; speedup vs baseline: 1.3927x; 1.3927x over previous
//
#include <hip/hip_runtime.h>
#include <hip/hip_bf16.h>

// ---------------------------------------------------------------------------
// GCN graph classifier: 2x GCNConv(relu) -> mean pool -> MLP -> sigmoid
// Round 2: bf16 intermediates (halve gather bytes), per-edge precomputed
// norm (kill random dinv gather), MFMA bf16 GEMMs. fp32 accumulation
// everywhere; CSR built on device each launch (int atomics only).
// ---------------------------------------------------------------------------

using short8 = __attribute__((ext_vector_type(8))) short;   // 8 bf16 (4 VGPR)
using f32x4  = __attribute__((ext_vector_type(4))) float;   // MFMA accum

__device__ inline unsigned short f2bf(float f) {  // RNE fp32 -> bf16
    unsigned u = __float_as_uint(f);
    u = (u + 0x7fff + ((u >> 16) & 1)) >> 16;
    return (unsigned short)u;
}
__device__ inline float bf2f(unsigned short b) {
    return __uint_as_float((unsigned)b << 16);
}

// ---- init: zero degree histogram and pooled accumulator -------------------
__global__ __launch_bounds__(256) void k_init(int* __restrict__ deg,
                                              float* __restrict__ pooled,
                                              int n) {
    int i = blockIdx.x * 256 + threadIdx.x;
    if (i < n) deg[i] = 0;
    if (i < 128) pooled[i] = 0.0f;
}

// ---- histogram of dst ------------------------------------------------------
__global__ __launch_bounds__(256) void k_hist(const int* __restrict__ dst,
                                              int* __restrict__ deg, int e) {
    int i = blockIdx.x * 256 + threadIdx.x;
    if (i < e) atomicAdd(&deg[dst[i]], 1);
}

// ---- dinv[i] = rsqrt(deg+1)  (self loop included) --------------------------
__global__ __launch_bounds__(256) void k_dinv(const int* __restrict__ deg,
                                              float* __restrict__ dinv, int n) {
    int i = blockIdx.x * 256 + threadIdx.x;
    if (i < n) dinv[i] = rsqrtf((float)deg[i] + 1.0f);
}

// ---- scan stage 1: per-block exclusive scan + block sums -------------------
__global__ __launch_bounds__(256) void k_scan1(const int* __restrict__ deg,
                                               int* __restrict__ rowptr,
                                               int* __restrict__ bsum, int n) {
    __shared__ int sh[256];
    int tid = threadIdx.x;
    int i = blockIdx.x * 256 + tid;
    int v = (i < n) ? deg[i] : 0;
    sh[tid] = v;
    __syncthreads();
    for (int ofs = 1; ofs < 256; ofs <<= 1) {
        int t = (tid >= ofs) ? sh[tid - ofs] : 0;
        __syncthreads();
        sh[tid] += t;
        __syncthreads();
    }
    if (i < n) rowptr[i] = sh[tid] - v;          // exclusive
    if (tid == 255) bsum[blockIdx.x] = sh[tid];  // inclusive total
}

// ---- scan stage 2: scan block sums (single block, nblocks <= 256) ----------
__global__ __launch_bounds__(256) void k_scan2(const int* __restrict__ bsum,
                                               int* __restrict__ bofs, int nb) {
    __shared__ int sh[256];
    int tid = threadIdx.x;
    int v = (tid < nb) ? bsum[tid] : 0;
    sh[tid] = v;
    __syncthreads();
    for (int ofs = 1; ofs < 256; ofs <<= 1) {
        int t = (tid >= ofs) ? sh[tid - ofs] : 0;
        __syncthreads();
        sh[tid] += t;
        __syncthreads();
    }
    bofs[tid] = sh[tid] - v;  // exclusive
}

// ---- scan stage 3: add block offsets; init cursor; rowptr[N]=E -------------
__global__ __launch_bounds__(256) void k_scan3(int* __restrict__ rowptr,
                                               const int* __restrict__ bofs,
                                               int* __restrict__ cursor, int n,
                                               int etot) {
    int i = blockIdx.x * 256 + threadIdx.x;
    if (i < n) {
        int rp = rowptr[i] + bofs[blockIdx.x];
        rowptr[i] = rp;
        cursor[i] = rp;
    }
    if (i == 0) rowptr[n] = etot;
}

// ---- scatter edges into CSR by dst; precompute per-edge norm ---------------
__global__ __launch_bounds__(256) void k_scatter(const int* __restrict__ ei,
                                                 const float* __restrict__ dinv,
                                                 int* __restrict__ cursor,
                                                 int* __restrict__ csr,
                                                 float* __restrict__ enorm,
                                                 int e) {
    int i = blockIdx.x * 256 + threadIdx.x;
    if (i < e) {
        int s = ei[i];
        int d = ei[e + i];
        int pos = atomicAdd(&cursor[d], 1);
        csr[pos] = s;
        enorm[pos] = dinv[s] * dinv[d];
    }
}

// ---- prep: convert both 128x128 weights to pre-fragged bf16 MFMA layout ----
// wf[((ct*4+ks)*64+l)*8+j] = W[ks*32 + (l>>4)*8 + j][ct*16 + (l&15)]
__global__ __launch_bounds__(256) void k_prepw(const float* __restrict__ w1,
                                               const float* __restrict__ w2,
                                               unsigned short* __restrict__ wf1,
                                               unsigned short* __restrict__ wf2) {
    int t = blockIdx.x * 256 + threadIdx.x;  // 0..32767
    int i = t & 16383;
    int j = i & 7;
    int l = (i >> 3) & 63;
    int ks = (i >> 9) & 3;
    int ct = (i >> 11) & 7;
    int k = ks * 32 + (l >> 4) * 8 + j;
    int c = ct * 16 + (l & 15);
    if (t < 16384)
        wf1[i] = f2bf(w1[k * 128 + c]);
    else
        wf2[i] = f2bf(w2[k * 128 + c]);
}

// ---- MFMA bf16 GEMM: C[nrows,128](bf16) = A[nrows,128] @ W[128,128] --------
// 4 waves/block, 16 rows/wave (64 rows/block). 16x16x32 frags:
//   A: row=lane&15, k=(lane>>4)*8+j ; B: col=lane&15, k=(lane>>4)*8+j
//   D: col=lane&15, row=(lane>>4)*4+reg   [measured: learn_hip m89]
template <bool AFP32>
__global__ __launch_bounds__(256) void k_gemm_mfma(
    const void* __restrict__ Ain, const unsigned short* __restrict__ Wf,
    unsigned short* __restrict__ Cout, int nrows) {
    const int tid = threadIdx.x;
    const int wave = tid >> 6, l = tid & 63;
    const int r0w = blockIdx.x * 64 + wave * 16;
    const int mrow = l & 15, koff = (l >> 4) * 8;
    int r = r0w + mrow;
    int rload = (r < nrows) ? r : 0;

    short8 afr[4];
    if (AFP32) {
        const float* A = (const float*)Ain;
#pragma unroll
        for (int ks = 0; ks < 4; ++ks) {
            const float4 lo = *(const float4*)&A[(size_t)rload * 128 + ks * 32 + koff];
            const float4 hi = *(const float4*)&A[(size_t)rload * 128 + ks * 32 + koff + 4];
            short8 t;
            t[0] = (short)f2bf(lo.x); t[1] = (short)f2bf(lo.y);
            t[2] = (short)f2bf(lo.z); t[3] = (short)f2bf(lo.w);
            t[4] = (short)f2bf(hi.x); t[5] = (short)f2bf(hi.y);
            t[6] = (short)f2bf(hi.z); t[7] = (short)f2bf(hi.w);
            afr[ks] = t;
        }
    } else {
        const unsigned short* A = (const unsigned short*)Ain;
#pragma unroll
        for (int ks = 0; ks < 4; ++ks)
            afr[ks] = *(const short8*)&A[(size_t)rload * 128 + ks * 32 + koff];
    }

    f32x4 acc[8];
#pragma unroll
    for (int ct = 0; ct < 8; ++ct) acc[ct] = (f32x4){0.f, 0.f, 0.f, 0.f};

#pragma unroll
    for (int ct = 0; ct < 8; ++ct) {
#pragma unroll
        for (int ks = 0; ks < 4; ++ks) {
            const short8 b = *(const short8*)&Wf[((ct * 4 + ks) * 64 + l) * 8];
            acc[ct] = __builtin_amdgcn_mfma_f32_16x16x32_bf16(afr[ks], b,
                                                              acc[ct], 0, 0, 0);
        }
    }

    const int rs0 = r0w + (l >> 4) * 4;
    const int cc = l & 15;
#pragma unroll
    for (int ct = 0; ct < 8; ++ct) {
#pragma unroll
        for (int i = 0; i < 4; ++i) {
            const int rr = rs0 + i;
            if (rr < nrows)
                Cout[(size_t)rr * 128 + ct * 16 + cc] = f2bf(acc[ct][i]);
        }
    }
}

// ---- aggregate (bf16 h): one wave per node; self-loop + bias + relu --------
__global__ __launch_bounds__(256) void k_agg_bf16(
    const unsigned short* __restrict__ h, const float* __restrict__ dinv,
    const int* __restrict__ rowptr, const int* __restrict__ csr,
    const float* __restrict__ enorm, const float* __restrict__ bias,
    unsigned short* __restrict__ outp, int n) {
    const int node = blockIdx.x * 4 + (threadIdx.x >> 6);
    if (node >= n) return;
    const int lane = threadIdx.x & 63;
    const float di = dinv[node];

    const float2 bp = *(const float2*)&bias[lane * 2];
    const unsigned hv = *(const unsigned*)&h[(size_t)node * 128 + lane * 2];
    float accx = bf2f((unsigned short)(hv & 0xffff)) * di * di;
    float accy = bf2f((unsigned short)(hv >> 16)) * di * di;

    int j = rowptr[node];
    const int end = rowptr[node + 1];
    for (; j + 3 < end; j += 4) {
        const int s0 = csr[j], s1 = csr[j + 1], s2 = csr[j + 2], s3 = csr[j + 3];
        const float n0 = enorm[j], n1 = enorm[j + 1], n2 = enorm[j + 2],
                    n3 = enorm[j + 3];
        const unsigned a0 = *(const unsigned*)&h[(size_t)s0 * 128 + lane * 2];
        const unsigned a1 = *(const unsigned*)&h[(size_t)s1 * 128 + lane * 2];
        const unsigned a2 = *(const unsigned*)&h[(size_t)s2 * 128 + lane * 2];
        const unsigned a3 = *(const unsigned*)&h[(size_t)s3 * 128 + lane * 2];
        accx += bf2f((unsigned short)(a0 & 0xffff)) * n0 +
                bf2f((unsigned short)(a1 & 0xffff)) * n1 +
                bf2f((unsigned short)(a2 & 0xffff)) * n2 +
                bf2f((unsigned short)(a3 & 0xffff)) * n3;
        accy += bf2f((unsigned short)(a0 >> 16)) * n0 +
                bf2f((unsigned short)(a1 >> 16)) * n1 +
                bf2f((unsigned short)(a2 >> 16)) * n2 +
                bf2f((unsigned short)(a3 >> 16)) * n3;
    }
    for (; j < end; ++j) {
        const int s0 = csr[j];
        const float n0 = enorm[j];
        const unsigned a0 = *(const unsigned*)&h[(size_t)s0 * 128 + lane * 2];
        accx += bf2f((unsigned short)(a0 & 0xffff)) * n0;
        accy += bf2f((unsigned short)(a0 >> 16)) * n0;
    }
    const unsigned short rx = f2bf(fmaxf(accx + bp.x, 0.f));
    const unsigned short ry = f2bf(fmaxf(accy + bp.y, 0.f));
    *(unsigned*)&outp[(size_t)node * 128 + lane * 2] =
        ((unsigned)ry << 16) | rx;
}

// ---- mean pool over bf16 [n,128]: block partials + atomic combine ----------
__global__ __launch_bounds__(256) void k_pool_bf16(
    const unsigned short* __restrict__ a, float* __restrict__ pooled,
    int npairs) {  // npairs = n*64 (uint = 2 cols)
    __shared__ float px[256], py[256];
    const int tid = threadIdx.x;
    float sx = 0.f, sy = 0.f;
    for (size_t idx = (size_t)blockIdx.x * 256 + tid; idx < (size_t)npairs;
         idx += (size_t)gridDim.x * 256) {
        const unsigned v = *(const unsigned*)&a[idx * 2];
        sx += bf2f((unsigned short)(v & 0xffff));
        sy += bf2f((unsigned short)(v >> 16));
    }
    px[tid] = sx;
    py[tid] = sy;
    __syncthreads();
    if (tid < 64) {
        const int c = tid;  // pair index within row = (global idx) & 63 == tid&63
        float ax = px[c] + px[c + 64] + px[c + 128] + px[c + 192];
        float ay = py[c] + py[c + 64] + py[c + 128] + py[c + 192];
        atomicAdd(&pooled[2 * c], ax);
        atomicAdd(&pooled[2 * c + 1], ay);
    }
}

// ---- MLP head: single block, 128 threads -----------------------------------
__global__ __launch_bounds__(128) void k_mlp(
    const float* __restrict__ pooled, const float* __restrict__ w11,
    const float* __restrict__ b11, const float* __restrict__ w12,
    const float* __restrict__ b12, const float* __restrict__ w21,
    const float* __restrict__ b21, const float* __restrict__ w22,
    const float* __restrict__ b22, float* __restrict__ out, int n) {
    __shared__ float g[128], t1[128], t2[128], t3[128], red[128];
    const int tid = threadIdx.x;
    g[tid] = pooled[tid] * (1.0f / (float)n);
    __syncthreads();

    float s = b11[tid];
    for (int k = 0; k < 128; ++k) s += g[k] * w11[k * 128 + tid];
    t1[tid] = fmaxf(s, 0.f);
    __syncthreads();

    s = b12[tid];
    for (int k = 0; k < 128; ++k) s += t1[k] * w12[k * 128 + tid];
    t2[tid] = s;
    __syncthreads();

    s = b21[tid];
    for (int k = 0; k < 128; ++k) s += t2[k] * w21[k * 128 + tid];
    t3[tid] = fmaxf(s, 0.f);
    __syncthreads();

    red[tid] = t3[tid] * w22[tid];
    __syncthreads();
    if (tid == 0) {
        float z = b22[0];
        for (int k = 0; k < 128; ++k) z += red[k];
        out[0] = 1.0f / (1.0f + expf(-z));
    }
}

extern "C" void kernel_launch(void* const* d_in, const int* in_sizes, int n_in,
                              void* d_out, int out_size, void* d_ws,
                              size_t ws_size, hipStream_t stream) {
    const float* x = (const float*)d_in[0];
    const int* ei = (const int*)d_in[1];
    const float* c1w = (const float*)d_in[2];
    const float* c1b = (const float*)d_in[3];
    const float* c2w = (const float*)d_in[4];
    const float* c2b = (const float*)d_in[5];
    const float* f1w1 = (const float*)d_in[6];
    const float* f1b1 = (const float*)d_in[7];
    const float* f1w2 = (const float*)d_in[8];
    const float* f1b2 = (const float*)d_in[9];
    const float* f2w1 = (const float*)d_in[10];
    const float* f2b1 = (const float*)d_in[11];
    const float* f2w2 = (const float*)d_in[12];
    const float* f2b2 = (const float*)d_in[13];
    float* out = (float*)d_out;

    const int N = in_sizes[0] / 128;
    const int E = in_sizes[1] / 2;

    char* ws = (char*)d_ws;
    size_t off = 0;
    auto alloc = [&](size_t b) {
        size_t o = off;
        off += (b + 255) & ~(size_t)255;
        return o;
    };
    int* deg = (int*)(ws + alloc((size_t)N * 4));
    float* dinv = (float*)(ws + alloc((size_t)N * 4));
    int* rowptr = (int*)(ws + alloc((size_t)(N + 1) * 4));
    int* cursor = (int*)(ws + alloc((size_t)N * 4));
    int* bsum = (int*)(ws + alloc(1024));
    int* bofs = (int*)(ws + alloc(1024));
    int* csr = (int*)(ws + alloc((size_t)E * 4));
    float* enorm = (float*)(ws + alloc((size_t)E * 4));
    float* pooled = (float*)(ws + alloc(512));
    unsigned short* wf1 = (unsigned short*)(ws + alloc(16384 * 2));
    unsigned short* wf2 = (unsigned short*)(ws + alloc(16384 * 2));
    unsigned short* hbuf = (unsigned short*)(ws + alloc((size_t)N * 128 * 2));
    unsigned short* abuf = (unsigned short*)(ws + alloc((size_t)N * 128 * 2));

    const int nbN = (N + 255) / 256;  // 196
    const int nbE = (E + 255) / 256;  // 3125
    const int nbG = (N + 63) / 64;    // 782

    k_init<<<nbN, 256, 0, stream>>>(deg, pooled, N);
    k_hist<<<nbE, 256, 0, stream>>>(ei + E, deg, E);
    k_dinv<<<nbN, 256, 0, stream>>>(deg, dinv, N);
    k_scan1<<<nbN, 256, 0, stream>>>(deg, rowptr, bsum, N);
    k_scan2<<<1, 256, 0, stream>>>(bsum, bofs, nbN);
    k_scan3<<<nbN, 256, 0, stream>>>(rowptr, bofs, cursor, N, E);
    k_scatter<<<nbE, 256, 0, stream>>>(ei, dinv, cursor, csr, enorm, E);
    k_prepw<<<128, 256, 0, stream>>>(c1w, c2w, wf1, wf2);

    k_gemm_mfma<true><<<nbG, 256, 0, stream>>>(x, wf1, hbuf, N);
    k_agg_bf16<<<(N + 3) / 4, 256, 0, stream>>>(hbuf, dinv, rowptr, csr, enorm,
                                                c1b, abuf, N);
    k_gemm_mfma<false><<<nbG, 256, 0, stream>>>(abuf, wf2, hbuf, N);
    k_agg_bf16<<<(N + 3) / 4, 256, 0, stream>>>(hbuf, dinv, rowptr, csr, enorm,
                                                c2b, abuf, N);

    k_pool_bf16<<<256, 256, 0, stream>>>(abuf, pooled, N * 64);
    k_mlp<<<1, 128, 0, stream>>>(pooled, f1w1, f1b1, f1w2, f1b2, f2w1, f2b1,
                                 f2w2, f2b2, out, N);
}

// Round 4
// 317.821 us; speedup vs baseline: 1.4028x; 1.0073x over previous
//
#include <hip/hip_runtime.h>
#include <hip/hip_bf16.h>

// ---------------------------------------------------------------------------
// GCN graph classifier: 2x GCNConv(relu) -> mean pool -> MLP -> sigmoid
// Round 3: pack (src, norm) into one 8B edge record -> single random write
// per edge in scatter (halves write-allocate traffic). bf16 intermediates,
// MFMA GEMMs, fp32 accumulation, CSR rebuilt on device each launch.
// ---------------------------------------------------------------------------

using short8 = __attribute__((ext_vector_type(8))) short;   // 8 bf16 (4 VGPR)
using f32x4  = __attribute__((ext_vector_type(4))) float;   // MFMA accum

__device__ inline unsigned short f2bf(float f) {  // RNE fp32 -> bf16
    unsigned u = __float_as_uint(f);
    u = (u + 0x7fff + ((u >> 16) & 1)) >> 16;
    return (unsigned short)u;
}
__device__ inline float bf2f(unsigned short b) {
    return __uint_as_float((unsigned)b << 16);
}

// ---- init: zero degree histogram and pooled accumulator -------------------
__global__ __launch_bounds__(256) void k_init(int* __restrict__ deg,
                                              float* __restrict__ pooled,
                                              int n) {
    int i = blockIdx.x * 256 + threadIdx.x;
    if (i < n) deg[i] = 0;
    if (i < 128) pooled[i] = 0.0f;
}

// ---- histogram of dst ------------------------------------------------------
__global__ __launch_bounds__(256) void k_hist(const int* __restrict__ dst,
                                              int* __restrict__ deg, int e) {
    int i = blockIdx.x * 256 + threadIdx.x;
    if (i < e) atomicAdd(&deg[dst[i]], 1);
}

// ---- dinv[i] = rsqrt(deg+1)  (self loop included) --------------------------
__global__ __launch_bounds__(256) void k_dinv(const int* __restrict__ deg,
                                              float* __restrict__ dinv, int n) {
    int i = blockIdx.x * 256 + threadIdx.x;
    if (i < n) dinv[i] = rsqrtf((float)deg[i] + 1.0f);
}

// ---- scan stage 1: per-block exclusive scan + block sums -------------------
__global__ __launch_bounds__(256) void k_scan1(const int* __restrict__ deg,
                                               int* __restrict__ rowptr,
                                               int* __restrict__ bsum, int n) {
    __shared__ int sh[256];
    int tid = threadIdx.x;
    int i = blockIdx.x * 256 + tid;
    int v = (i < n) ? deg[i] : 0;
    sh[tid] = v;
    __syncthreads();
    for (int ofs = 1; ofs < 256; ofs <<= 1) {
        int t = (tid >= ofs) ? sh[tid - ofs] : 0;
        __syncthreads();
        sh[tid] += t;
        __syncthreads();
    }
    if (i < n) rowptr[i] = sh[tid] - v;          // exclusive
    if (tid == 255) bsum[blockIdx.x] = sh[tid];  // inclusive total
}

// ---- scan stage 2: scan block sums (single block, nblocks <= 256) ----------
__global__ __launch_bounds__(256) void k_scan2(const int* __restrict__ bsum,
                                               int* __restrict__ bofs, int nb) {
    __shared__ int sh[256];
    int tid = threadIdx.x;
    int v = (tid < nb) ? bsum[tid] : 0;
    sh[tid] = v;
    __syncthreads();
    for (int ofs = 1; ofs < 256; ofs <<= 1) {
        int t = (tid >= ofs) ? sh[tid - ofs] : 0;
        __syncthreads();
        sh[tid] += t;
        __syncthreads();
    }
    bofs[tid] = sh[tid] - v;  // exclusive
}

// ---- scan stage 3: add block offsets; init cursor; rowptr[N]=E -------------
__global__ __launch_bounds__(256) void k_scan3(int* __restrict__ rowptr,
                                               const int* __restrict__ bofs,
                                               int* __restrict__ cursor, int n,
                                               int etot) {
    int i = blockIdx.x * 256 + threadIdx.x;
    if (i < n) {
        int rp = rowptr[i] + bofs[blockIdx.x];
        rowptr[i] = rp;
        cursor[i] = rp;
    }
    if (i == 0) rowptr[n] = etot;
}

// ---- scatter: one packed 8B record per edge (src, norm) --------------------
__global__ __launch_bounds__(256) void k_scatter(const int* __restrict__ ei,
                                                 const float* __restrict__ dinv,
                                                 int* __restrict__ cursor,
                                                 uint2* __restrict__ edata,
                                                 int e) {
    int i = blockIdx.x * 256 + threadIdx.x;
    if (i < e) {
        int s = ei[i];
        int d = ei[e + i];
        int pos = atomicAdd(&cursor[d], 1);
        uint2 rec;
        rec.x = (unsigned)s;
        rec.y = __float_as_uint(dinv[s] * dinv[d]);
        edata[pos] = rec;
    }
}

// ---- prep: convert both 128x128 weights to pre-fragged bf16 MFMA layout ----
// wf[((ct*4+ks)*64+l)*8+j] = W[ks*32 + (l>>4)*8 + j][ct*16 + (l&15)]
__global__ __launch_bounds__(256) void k_prepw(const float* __restrict__ w1,
                                               const float* __restrict__ w2,
                                               unsigned short* __restrict__ wf1,
                                               unsigned short* __restrict__ wf2) {
    int t = blockIdx.x * 256 + threadIdx.x;  // 0..32767
    int i = t & 16383;
    int j = i & 7;
    int l = (i >> 3) & 63;
    int ks = (i >> 9) & 3;
    int ct = (i >> 11) & 7;
    int k = ks * 32 + (l >> 4) * 8 + j;
    int c = ct * 16 + (l & 15);
    if (t < 16384)
        wf1[i] = f2bf(w1[k * 128 + c]);
    else
        wf2[i] = f2bf(w2[k * 128 + c]);
}

// ---- MFMA bf16 GEMM: C[nrows,128](bf16) = A[nrows,128] @ W[128,128] --------
// 4 waves/block, 16 rows/wave (64 rows/block). 16x16x32 frags:
//   A: row=lane&15, k=(lane>>4)*8+j ; B: col=lane&15, k=(lane>>4)*8+j
//   D: col=lane&15, row=(lane>>4)*4+reg   [measured: learn_hip m89]
template <bool AFP32>
__global__ __launch_bounds__(256) void k_gemm_mfma(
    const void* __restrict__ Ain, const unsigned short* __restrict__ Wf,
    unsigned short* __restrict__ Cout, int nrows) {
    const int tid = threadIdx.x;
    const int wave = tid >> 6, l = tid & 63;
    const int r0w = blockIdx.x * 64 + wave * 16;
    const int mrow = l & 15, koff = (l >> 4) * 8;
    int r = r0w + mrow;
    int rload = (r < nrows) ? r : 0;

    short8 afr[4];
    if (AFP32) {
        const float* A = (const float*)Ain;
#pragma unroll
        for (int ks = 0; ks < 4; ++ks) {
            const float4 lo = *(const float4*)&A[(size_t)rload * 128 + ks * 32 + koff];
            const float4 hi = *(const float4*)&A[(size_t)rload * 128 + ks * 32 + koff + 4];
            short8 t;
            t[0] = (short)f2bf(lo.x); t[1] = (short)f2bf(lo.y);
            t[2] = (short)f2bf(lo.z); t[3] = (short)f2bf(lo.w);
            t[4] = (short)f2bf(hi.x); t[5] = (short)f2bf(hi.y);
            t[6] = (short)f2bf(hi.z); t[7] = (short)f2bf(hi.w);
            afr[ks] = t;
        }
    } else {
        const unsigned short* A = (const unsigned short*)Ain;
#pragma unroll
        for (int ks = 0; ks < 4; ++ks)
            afr[ks] = *(const short8*)&A[(size_t)rload * 128 + ks * 32 + koff];
    }

    f32x4 acc[8];
#pragma unroll
    for (int ct = 0; ct < 8; ++ct) acc[ct] = (f32x4){0.f, 0.f, 0.f, 0.f};

#pragma unroll
    for (int ct = 0; ct < 8; ++ct) {
#pragma unroll
        for (int ks = 0; ks < 4; ++ks) {
            const short8 b = *(const short8*)&Wf[((ct * 4 + ks) * 64 + l) * 8];
            acc[ct] = __builtin_amdgcn_mfma_f32_16x16x32_bf16(afr[ks], b,
                                                              acc[ct], 0, 0, 0);
        }
    }

    const int rs0 = r0w + (l >> 4) * 4;
    const int cc = l & 15;
#pragma unroll
    for (int ct = 0; ct < 8; ++ct) {
#pragma unroll
        for (int i = 0; i < 4; ++i) {
            const int rr = rs0 + i;
            if (rr < nrows)
                Cout[(size_t)rr * 128 + ct * 16 + cc] = f2bf(acc[ct][i]);
        }
    }
}

// ---- aggregate (bf16 h): one wave per node; self-loop + bias + relu --------
__global__ __launch_bounds__(256) void k_agg_bf16(
    const unsigned short* __restrict__ h, const float* __restrict__ dinv,
    const int* __restrict__ rowptr, const uint2* __restrict__ edata,
    const float* __restrict__ bias, unsigned short* __restrict__ outp, int n) {
    const int node = blockIdx.x * 4 + (threadIdx.x >> 6);
    if (node >= n) return;
    const int lane = threadIdx.x & 63;
    const float di = dinv[node];

    const float2 bp = *(const float2*)&bias[lane * 2];
    const unsigned hv = *(const unsigned*)&h[(size_t)node * 128 + lane * 2];
    float accx = bf2f((unsigned short)(hv & 0xffff)) * di * di;
    float accy = bf2f((unsigned short)(hv >> 16)) * di * di;

    int j = rowptr[node];
    const int end = rowptr[node + 1];
    for (; j + 3 < end; j += 4) {
        const uint2 e0 = edata[j], e1 = edata[j + 1], e2 = edata[j + 2],
                    e3 = edata[j + 3];
        const float n0 = __uint_as_float(e0.y), n1 = __uint_as_float(e1.y),
                    n2 = __uint_as_float(e2.y), n3 = __uint_as_float(e3.y);
        const unsigned a0 = *(const unsigned*)&h[(size_t)e0.x * 128 + lane * 2];
        const unsigned a1 = *(const unsigned*)&h[(size_t)e1.x * 128 + lane * 2];
        const unsigned a2 = *(const unsigned*)&h[(size_t)e2.x * 128 + lane * 2];
        const unsigned a3 = *(const unsigned*)&h[(size_t)e3.x * 128 + lane * 2];
        accx += bf2f((unsigned short)(a0 & 0xffff)) * n0 +
                bf2f((unsigned short)(a1 & 0xffff)) * n1 +
                bf2f((unsigned short)(a2 & 0xffff)) * n2 +
                bf2f((unsigned short)(a3 & 0xffff)) * n3;
        accy += bf2f((unsigned short)(a0 >> 16)) * n0 +
                bf2f((unsigned short)(a1 >> 16)) * n1 +
                bf2f((unsigned short)(a2 >> 16)) * n2 +
                bf2f((unsigned short)(a3 >> 16)) * n3;
    }
    for (; j < end; ++j) {
        const uint2 e0 = edata[j];
        const float n0 = __uint_as_float(e0.y);
        const unsigned a0 = *(const unsigned*)&h[(size_t)e0.x * 128 + lane * 2];
        accx += bf2f((unsigned short)(a0 & 0xffff)) * n0;
        accy += bf2f((unsigned short)(a0 >> 16)) * n0;
    }
    const unsigned short rx = f2bf(fmaxf(accx + bp.x, 0.f));
    const unsigned short ry = f2bf(fmaxf(accy + bp.y, 0.f));
    *(unsigned*)&outp[(size_t)node * 128 + lane * 2] =
        ((unsigned)ry << 16) | rx;
}

// ---- mean pool over bf16 [n,128]: block partials + atomic combine ----------
__global__ __launch_bounds__(256) void k_pool_bf16(
    const unsigned short* __restrict__ a, float* __restrict__ pooled,
    int npairs) {  // npairs = n*64 (uint = 2 cols)
    __shared__ float px[256], py[256];
    const int tid = threadIdx.x;
    float sx = 0.f, sy = 0.f;
    for (size_t idx = (size_t)blockIdx.x * 256 + tid; idx < (size_t)npairs;
         idx += (size_t)gridDim.x * 256) {
        const unsigned v = *(const unsigned*)&a[idx * 2];
        sx += bf2f((unsigned short)(v & 0xffff));
        sy += bf2f((unsigned short)(v >> 16));
    }
    px[tid] = sx;
    py[tid] = sy;
    __syncthreads();
    if (tid < 64) {
        const int c = tid;  // pair index within row = (global idx) & 63 == tid&63
        float ax = px[c] + px[c + 64] + px[c + 128] + px[c + 192];
        float ay = py[c] + py[c + 64] + py[c + 128] + py[c + 192];
        atomicAdd(&pooled[2 * c], ax);
        atomicAdd(&pooled[2 * c + 1], ay);
    }
}

// ---- MLP head: single block, 128 threads -----------------------------------
__global__ __launch_bounds__(128) void k_mlp(
    const float* __restrict__ pooled, const float* __restrict__ w11,
    const float* __restrict__ b11, const float* __restrict__ w12,
    const float* __restrict__ b12, const float* __restrict__ w21,
    const float* __restrict__ b21, const float* __restrict__ w22,
    const float* __restrict__ b22, float* __restrict__ out, int n) {
    __shared__ float g[128], t1[128], t2[128], t3[128], red[128];
    const int tid = threadIdx.x;
    g[tid] = pooled[tid] * (1.0f / (float)n);
    __syncthreads();

    float s = b11[tid];
    for (int k = 0; k < 128; ++k) s += g[k] * w11[k * 128 + tid];
    t1[tid] = fmaxf(s, 0.f);
    __syncthreads();

    s = b12[tid];
    for (int k = 0; k < 128; ++k) s += t1[k] * w12[k * 128 + tid];
    t2[tid] = s;
    __syncthreads();

    s = b21[tid];
    for (int k = 0; k < 128; ++k) s += t2[k] * w21[k * 128 + tid];
    t3[tid] = fmaxf(s, 0.f);
    __syncthreads();

    red[tid] = t3[tid] * w22[tid];
    __syncthreads();
    if (tid == 0) {
        float z = b22[0];
        for (int k = 0; k < 128; ++k) z += red[k];
        out[0] = 1.0f / (1.0f + expf(-z));
    }
}

extern "C" void kernel_launch(void* const* d_in, const int* in_sizes, int n_in,
                              void* d_out, int out_size, void* d_ws,
                              size_t ws_size, hipStream_t stream) {
    const float* x = (const float*)d_in[0];
    const int* ei = (const int*)d_in[1];
    const float* c1w = (const float*)d_in[2];
    const float* c1b = (const float*)d_in[3];
    const float* c2w = (const float*)d_in[4];
    const float* c2b = (const float*)d_in[5];
    const float* f1w1 = (const float*)d_in[6];
    const float* f1b1 = (const float*)d_in[7];
    const float* f1w2 = (const float*)d_in[8];
    const float* f1b2 = (const float*)d_in[9];
    const float* f2w1 = (const float*)d_in[10];
    const float* f2b1 = (const float*)d_in[11];
    const float* f2w2 = (const float*)d_in[12];
    const float* f2b2 = (const float*)d_in[13];
    float* out = (float*)d_out;

    const int N = in_sizes[0] / 128;
    const int E = in_sizes[1] / 2;

    char* ws = (char*)d_ws;
    size_t off = 0;
    auto alloc = [&](size_t b) {
        size_t o = off;
        off += (b + 255) & ~(size_t)255;
        return o;
    };
    int* deg = (int*)(ws + alloc((size_t)N * 4));
    float* dinv = (float*)(ws + alloc((size_t)N * 4));
    int* rowptr = (int*)(ws + alloc((size_t)(N + 1) * 4));
    int* cursor = (int*)(ws + alloc((size_t)N * 4));
    int* bsum = (int*)(ws + alloc(1024));
    int* bofs = (int*)(ws + alloc(1024));
    uint2* edata = (uint2*)(ws + alloc((size_t)E * 8));
    float* pooled = (float*)(ws + alloc(512));
    unsigned short* wf1 = (unsigned short*)(ws + alloc(16384 * 2));
    unsigned short* wf2 = (unsigned short*)(ws + alloc(16384 * 2));
    unsigned short* hbuf = (unsigned short*)(ws + alloc((size_t)N * 128 * 2));
    unsigned short* abuf = (unsigned short*)(ws + alloc((size_t)N * 128 * 2));

    const int nbN = (N + 255) / 256;  // 196
    const int nbE = (E + 255) / 256;  // 3125
    const int nbG = (N + 63) / 64;    // 782

    k_init<<<nbN, 256, 0, stream>>>(deg, pooled, N);
    k_hist<<<nbE, 256, 0, stream>>>(ei + E, deg, E);
    k_dinv<<<nbN, 256, 0, stream>>>(deg, dinv, N);
    k_scan1<<<nbN, 256, 0, stream>>>(deg, rowptr, bsum, N);
    k_scan2<<<1, 256, 0, stream>>>(bsum, bofs, nbN);
    k_scan3<<<nbN, 256, 0, stream>>>(rowptr, bofs, cursor, N, E);
    k_scatter<<<nbE, 256, 0, stream>>>(ei, dinv, cursor, edata, E);
    k_prepw<<<128, 256, 0, stream>>>(c1w, c2w, wf1, wf2);

    k_gemm_mfma<true><<<nbG, 256, 0, stream>>>(x, wf1, hbuf, N);
    k_agg_bf16<<<(N + 3) / 4, 256, 0, stream>>>(hbuf, dinv, rowptr, edata, c1b,
                                                abuf, N);
    k_gemm_mfma<false><<<nbG, 256, 0, stream>>>(abuf, wf2, hbuf, N);
    k_agg_bf16<<<(N + 3) / 4, 256, 0, stream>>>(hbuf, dinv, rowptr, edata, c2b,
                                                abuf, N);

    k_pool_bf16<<<256, 256, 0, stream>>>(abuf, pooled, N * 64);
    k_mlp<<<1, 128, 0, stream>>>(pooled, f1w1, f1b1, f1w2, f1b2, f2w1, f2b1,
                                 f2w2, f2b2, out, N);
}